// Round 1
// baseline (164.848 us; speedup 1.0000x reference)
//
#include <hip/hip_runtime.h>
#include <math.h>

#define EPSF 1e-5f

// dims
#define BB 4
#define LL 197
#define DD 128
#define HH 8
#define DK 16
#define FF 256
#define PP 8
#define NC 1000
#define BL (BB*LL)   // 788

// ---------------------------------------------------------------------------
// K1: patchify + patch embed + cls/pos + tropical BN + fused LN1(layer 0)
// grid 197 blocks x 128 threads, 4 rows per block
// ---------------------------------------------------------------------------
__global__ __launch_bounds__(128) void k_patch_ln(
    const float* __restrict__ x, const float* __restrict__ pwm, const float* __restrict__ pbv,
    const float* __restrict__ cls, const float* __restrict__ pos,
    const float* __restrict__ bng, const float* __restrict__ bnb,
    const float* __restrict__ bnm, const float* __restrict__ bnr,
    const float* __restrict__ lw, const float* __restrict__ lb,
    float* __restrict__ h, float* __restrict__ hn)
{
    __shared__ float xp[4][768];
    __shared__ float redS[4][2], redS2[4][2];
    int d = threadIdx.x, r0 = blockIdx.x * 4;

    for (int r = 0; r < 4; ++r) {
        int row = r0 + r, l = row % LL, b = row / LL;
        if (l > 0) {
            int patch = l - 1, ph = patch / 14, pc = patch % 14;
            for (int i = d; i < 768; i += 128) {
                int c = i >> 8, rr = (i >> 4) & 15, cc = i & 15;
                xp[r][i] = x[((b * 3 + c) * 224 + ph * 16 + rr) * 224 + pc * 16 + cc];
            }
        }
    }
    __syncthreads();

    float acc[4] = {0.f, 0.f, 0.f, 0.f};
    const float4* w4 = (const float4*)(pwm + d * 768);
    for (int i4 = 0; i4 < 192; ++i4) {
        float4 w = w4[i4];
        #pragma unroll
        for (int r = 0; r < 4; ++r) {
            float4 a = ((const float4*)xp[r])[i4];
            acc[r] = fmaf(a.x, w.x, fmaf(a.y, w.y, fmaf(a.z, w.z, fmaf(a.w, w.w, acc[r]))));
        }
    }

    float hv[4];
    #pragma unroll
    for (int r = 0; r < 4; ++r) {
        int row = r0 + r, l = row % LL;
        float v = (l == 0) ? cls[d] : (acc[r] + pbv[d]);
        v += pos[l * DD + d];
        v = bng[d] * ((v - bnm[d]) / (bnr[d] + EPSF)) + bnb[d];
        h[row * DD + d] = v;
        hv[r] = v;
    }

    // fused LN over each row (128 values across 128 threads = 2 waves)
    float s[4], s2[4];
    #pragma unroll
    for (int r = 0; r < 4; ++r) { s[r] = hv[r]; s2[r] = hv[r] * hv[r]; }
    #pragma unroll
    for (int o = 1; o < 64; o <<= 1) {
        #pragma unroll
        for (int r = 0; r < 4; ++r) { s[r] += __shfl_xor(s[r], o); s2[r] += __shfl_xor(s2[r], o); }
    }
    int wid = d >> 6;
    if ((d & 63) == 0) {
        #pragma unroll
        for (int r = 0; r < 4; ++r) { redS[r][wid] = s[r]; redS2[r][wid] = s2[r]; }
    }
    __syncthreads();
    #pragma unroll
    for (int r = 0; r < 4; ++r) {
        float S = redS[r][0] + redS[r][1], S2 = redS2[r][0] + redS2[r][1];
        float mu = S * (1.f / 128.f);
        float var = S2 * (1.f / 128.f) - mu * mu;
        float rr = rsqrtf(var + EPSF);
        hn[(r0 + r) * DD + d] = (hv[r] - mu) * rr * lw[d] + lb[d];
    }
}

// ---------------------------------------------------------------------------
// K2: tropical Q, K + classical V + sigmoid gate.  grid 197 x 128, 4 rows/blk
// ---------------------------------------------------------------------------
__global__ __launch_bounds__(128) void k_qkvg(
    const float* __restrict__ hn,
    const float* __restrict__ wq, const float* __restrict__ bq,
    const float* __restrict__ wk, const float* __restrict__ bk,
    const float* __restrict__ wv, const float* __restrict__ bv,
    const float* __restrict__ gw, const float* __restrict__ gb,
    float* __restrict__ Q, float* __restrict__ K, float* __restrict__ V,
    float* __restrict__ g)
{
    __shared__ float xs[4][128];
    int d = threadIdx.x, r0 = blockIdx.x * 4;
    for (int idx = d; idx < 512; idx += 128) xs[idx >> 7][idx & 127] = hn[r0 * DD + idx];
    __syncthreads();

    float qa[4], ka[4], va[4];
    #pragma unroll
    for (int r = 0; r < 4; ++r) { qa[r] = -1e30f; ka[r] = -1e30f; va[r] = 0.f; }

    const float4* q4 = (const float4*)(wq + d * 128);
    const float4* k4 = (const float4*)(wk + d * 128);
    const float4* v4 = (const float4*)(wv + d * 128);
    for (int i4 = 0; i4 < 32; ++i4) {
        float4 wqv = q4[i4], wkv = k4[i4], wvv = v4[i4];
        #pragma unroll
        for (int r = 0; r < 4; ++r) {
            float4 a = ((const float4*)xs[r])[i4];
            qa[r] = fmaxf(qa[r], fmaxf(fmaxf(a.x + wqv.x, a.y + wqv.y), fmaxf(a.z + wqv.z, a.w + wqv.w)));
            ka[r] = fmaxf(ka[r], fmaxf(fmaxf(a.x + wkv.x, a.y + wkv.y), fmaxf(a.z + wkv.z, a.w + wkv.w)));
            va[r] = fmaf(a.x, wvv.x, fmaf(a.y, wvv.y, fmaf(a.z, wvv.z, fmaf(a.w, wvv.w, va[r]))));
        }
    }
    #pragma unroll
    for (int r = 0; r < 4; ++r) {
        int row = r0 + r;
        Q[row * DD + d] = qa[r] + bq[d];
        K[row * DD + d] = ka[r] + bk[d];
        V[row * DD + d] = va[r] + bv[d];
    }
    if (d < 32) {
        int r = d >> 3, hh = d & 7, row = r0 + r;
        float acc = gb[hh];
        for (int i = 0; i < 128; ++i) acc = fmaf(xs[r][i], gw[hh * 128 + i], acc);
        g[row * HH + hh] = 1.f / (1.f + __expf(-acc));
    }
}

// ---------------------------------------------------------------------------
// K3: fused attention. grid = B*H*7 blocks x 256 threads.
// 32 queries per block; 8 lanes per query split the k-range (online softmax,
// butterfly merge at the end).
// ---------------------------------------------------------------------------
__global__ __launch_bounds__(256) void k_attn(
    const float* __restrict__ Qd, const float* __restrict__ Kd,
    const float* __restrict__ Vd, const float* __restrict__ gd,
    const float* __restrict__ tempL, float* __restrict__ ao)
{
    __shared__ float Ks[LL * DK];
    __shared__ float Vs[LL * DK];
    int bid = blockIdx.x;
    int qc = bid % 7, bh = bid / 7;
    int hh = bh & 7, b = bh >> 3;
    int t = threadIdx.x;
    size_t base = (size_t)(b * LL) * DD + hh * DK;

    for (int idx = t; idx < LL * DK; idx += 256) {
        int l = idx >> 4, j = idx & 15;
        Ks[idx] = Kd[base + (size_t)l * DD + j];
        Vs[idx] = Vd[base + (size_t)l * DD + j];
    }
    __syncthreads();

    int q = qc * 32 + (t >> 3);
    int j8 = t & 7;
    if (q >= LL) return;

    float Qr[16];
    {
        const float4* qp = (const float4*)(Qd + base + (size_t)q * DD);
        #pragma unroll
        for (int u = 0; u < 4; ++u) {
            float4 v = qp[u];
            Qr[4 * u] = v.x; Qr[4 * u + 1] = v.y; Qr[4 * u + 2] = v.z; Qr[4 * u + 3] = v.w;
        }
    }
    float gq = gd[(b * LL + q) * HH + hh];
    float it = 0.25f / tempL[hh];          // scale * 1/temp
    float gg = gq * it, cg = (1.f - gq) * it;

    float m = -1e30f, lsum = 0.f, o[16];
    #pragma unroll
    for (int j = 0; j < 16; ++j) o[j] = 0.f;

    for (int k = j8; k < LL; k += 8) {
        const float* kr = Ks + k * DK;
        float cs = 0.f, ts = -1e30f;
        #pragma unroll
        for (int j = 0; j < 16; ++j) {
            float kv = kr[j];
            cs = fmaf(Qr[j], kv, cs);
            ts = fmaxf(ts, Qr[j] + kv);
        }
        float sc = fmaf(gg, ts, cg * cs);
        if (sc > m) {
            float c = __expf(m - sc);
            lsum *= c;
            #pragma unroll
            for (int j = 0; j < 16; ++j) o[j] *= c;
            m = sc;
        }
        float p = __expf(sc - m);
        lsum += p;
        const float* vr = Vs + k * DK;
        #pragma unroll
        for (int j = 0; j < 16; ++j) o[j] = fmaf(p, vr[j], o[j]);
    }

    // merge the 8 per-lane online-softmax states (butterfly)
    #pragma unroll
    for (int mask = 1; mask < 8; mask <<= 1) {
        float mo = __shfl_xor(m, mask);
        float lo = __shfl_xor(lsum, mask);
        float mn = fmaxf(m, mo);
        float ea = __expf(m - mn), eb = __expf(mo - mn);
        lsum = lsum * ea + lo * eb;
        #pragma unroll
        for (int j = 0; j < 16; ++j) {
            float oo = __shfl_xor(o[j], mask);
            o[j] = o[j] * ea + oo * eb;
        }
        m = mn;
    }

    if (j8 == 0) {
        float inv = 1.f / lsum;
        float* orow = ao + base + (size_t)q * DD;
        #pragma unroll
        for (int j = 0; j < 16; ++j) orow[j] = o[j] * inv;
    }
}

// ---------------------------------------------------------------------------
// K4/K6: projection (IN -> 128) + residual into h + fused LayerNorm -> hnout
// grid 197 x 128, 4 rows/block
// ---------------------------------------------------------------------------
template <int IN>
__global__ __launch_bounds__(128) void k_proj_res_ln(
    const float* __restrict__ in, const float* __restrict__ W, const float* __restrict__ bias,
    float* __restrict__ h, const float* __restrict__ lw, const float* __restrict__ lb,
    float* __restrict__ hnout)
{
    __shared__ float xs[4][IN];
    __shared__ float redS[4][2], redS2[4][2];
    int d = threadIdx.x, r0 = blockIdx.x * 4;
    for (int idx = d; idx < 4 * IN; idx += 128) xs[idx / IN][idx % IN] = in[r0 * IN + idx];
    __syncthreads();

    float acc[4] = {0.f, 0.f, 0.f, 0.f};
    const float4* w4 = (const float4*)(W + d * IN);
    for (int i4 = 0; i4 < IN / 4; ++i4) {
        float4 w = w4[i4];
        #pragma unroll
        for (int r = 0; r < 4; ++r) {
            float4 a = ((const float4*)xs[r])[i4];
            acc[r] = fmaf(a.x, w.x, fmaf(a.y, w.y, fmaf(a.z, w.z, fmaf(a.w, w.w, acc[r]))));
        }
    }

    float hv[4], s[4], s2[4];
    #pragma unroll
    for (int r = 0; r < 4; ++r) {
        int row = r0 + r;
        hv[r] = h[row * DD + d] + acc[r] + bias[d];
        h[row * DD + d] = hv[r];
        s[r] = hv[r]; s2[r] = hv[r] * hv[r];
    }
    #pragma unroll
    for (int o = 1; o < 64; o <<= 1) {
        #pragma unroll
        for (int r = 0; r < 4; ++r) { s[r] += __shfl_xor(s[r], o); s2[r] += __shfl_xor(s2[r], o); }
    }
    int wid = d >> 6;
    if ((d & 63) == 0) {
        #pragma unroll
        for (int r = 0; r < 4; ++r) { redS[r][wid] = s[r]; redS2[r][wid] = s2[r]; }
    }
    __syncthreads();
    #pragma unroll
    for (int r = 0; r < 4; ++r) {
        float S = redS[r][0] + redS[r][1], S2 = redS2[r][0] + redS2[r][1];
        float mu = S * (1.f / 128.f);
        float var = S2 * (1.f / 128.f) - mu * mu;
        float rr = rsqrtf(var + EPSF);
        hnout[(r0 + r) * DD + d] = (hv[r] - mu) * rr * lw[d] + lb[d];
    }
}

// ---------------------------------------------------------------------------
// K5: FFN front half: tropical unit + lf max/min mix + exact GELU + fuse gate
// grid 197 x 256, 4 rows/block
// ---------------------------------------------------------------------------
__global__ __launch_bounds__(256) void k_ffn(
    const float* __restrict__ hn2,
    const float* __restrict__ tw, const float* __restrict__ tb,
    const float* __restrict__ la, const float* __restrict__ lc, const float* __restrict__ lg,
    const float* __restrict__ cw, const float* __restrict__ cb,
    const float* __restrict__ fw, const float* __restrict__ fb,
    float* __restrict__ fused)
{
    __shared__ float xs[4][128];
    int f = threadIdx.x, r0 = blockIdx.x * 4;
    for (int idx = f; idx < 512; idx += 256) xs[idx >> 7][idx & 127] = hn2[r0 * DD + idx];
    __syncthreads();

    float ta[4], ca[4], ga[4];
    #pragma unroll
    for (int r = 0; r < 4; ++r) { ta[r] = -1e30f; ca[r] = 0.f; ga[r] = 0.f; }

    const float4* t4 = (const float4*)(tw + f * 128);
    const float4* c4 = (const float4*)(cw + f * 128);
    const float4* f4 = (const float4*)(fw + f * 128);
    for (int i4 = 0; i4 < 32; ++i4) {
        float4 wt = t4[i4], wc = c4[i4], wf = f4[i4];
        #pragma unroll
        for (int r = 0; r < 4; ++r) {
            float4 a = ((const float4*)xs[r])[i4];
            ta[r] = fmaxf(ta[r], fmaxf(fmaxf(a.x + wt.x, a.y + wt.y), fmaxf(a.z + wt.z, a.w + wt.w)));
            ca[r] = fmaf(a.x, wc.x, fmaf(a.y, wc.y, fmaf(a.z, wc.z, fmaf(a.w, wc.w, ca[r]))));
            ga[r] = fmaf(a.x, wf.x, fmaf(a.y, wf.y, fmaf(a.z, wf.z, fmaf(a.w, wf.w, ga[r]))));
        }
    }

    float gl = 1.f / (1.f + __expf(-lg[f]));
    float lav[8], lcv[8];
    #pragma unroll
    for (int p = 0; p < 8; ++p) { lav[p] = la[p * FF + f]; lcv[p] = lc[p * FF + f]; }

    #pragma unroll
    for (int r = 0; r < 4; ++r) {
        float z = ta[r] + tb[f];
        float mx = -1e30f, mn = 1e30f;
        #pragma unroll
        for (int p = 0; p < 8; ++p) {
            float zp = fmaf(z, lav[p], lcv[p]);
            mx = fmaxf(mx, zp);
            mn = fminf(mn, zp);
        }
        float trop = gl * mx + (1.f - gl) * mn;
        float xc = ca[r] + cb[f];
        float cla = 0.5f * xc * (1.f + erff(xc * 0.70710678118654752f));
        float gf = 1.f / (1.f + __expf(-(ga[r] + fb[f])));
        fused[(r0 + r) * FF + f] = gf * trop + (1.f - gf) * cla;
    }
}

// ---------------------------------------------------------------------------
// K7: classifier head on the (already final-LN'd) cls rows.
// grid 16 (= B*4) x 256
// ---------------------------------------------------------------------------
__global__ __launch_bounds__(256) void k_head(
    const float* __restrict__ hn, const float* __restrict__ hw,
    const float* __restrict__ hb, float* __restrict__ out)
{
    __shared__ float hs[128];
    int b = blockIdx.x >> 2, nc = blockIdx.x & 3, t = threadIdx.x;
    if (t < 128) hs[t] = hn[(size_t)b * LL * DD + t];
    __syncthreads();
    int n = nc * 256 + t;
    if (n < NC) {
        const float4* wr = (const float4*)(hw + n * 128);
        const float4* xr = (const float4*)hs;
        float acc = hb[n];
        for (int i = 0; i < 32; ++i) {
            float4 w = wr[i], a = xr[i];
            acc = fmaf(w.x, a.x, fmaf(w.y, a.y, fmaf(w.z, a.z, fmaf(w.w, a.w, acc))));
        }
        out[b * NC + n] = acc;
    }
}

// ---------------------------------------------------------------------------
extern "C" void kernel_launch(void* const* d_in, const int* in_sizes, int n_in,
                              void* d_out, int out_size, void* d_ws, size_t ws_size,
                              hipStream_t stream)
{
    const float* x        = (const float*)d_in[0];
    const float* patch_w  = (const float*)d_in[1];
    const float* patch_b  = (const float*)d_in[2];
    const float* cls_tok  = (const float*)d_in[3];
    const float* pos_emb  = (const float*)d_in[4];
    const float* bn_gamma = (const float*)d_in[5];
    const float* bn_beta  = (const float*)d_in[6];
    const float* bn_rmax  = (const float*)d_in[7];
    const float* bn_rrng  = (const float*)d_in[8];
    const float* n1_w     = (const float*)d_in[9];
    const float* n1_b     = (const float*)d_in[10];
    const float* n2_w     = (const float*)d_in[11];
    const float* n2_b     = (const float*)d_in[12];
    const float* wq       = (const float*)d_in[13];
    const float* bq       = (const float*)d_in[14];
    const float* wk       = (const float*)d_in[15];
    const float* bk       = (const float*)d_in[16];
    const float* wv       = (const float*)d_in[17];
    const float* bv       = (const float*)d_in[18];
    const float* wo       = (const float*)d_in[19];
    const float* bo       = (const float*)d_in[20];
    const float* gate_w   = (const float*)d_in[21];
    const float* gate_b   = (const float*)d_in[22];
    const float* temp     = (const float*)d_in[23];
    const float* tu_w     = (const float*)d_in[24];
    const float* tu_b     = (const float*)d_in[25];
    const float* lf_a     = (const float*)d_in[26];
    const float* lf_c     = (const float*)d_in[27];
    const float* lf_gate  = (const float*)d_in[28];
    const float* cu_w     = (const float*)d_in[29];
    const float* cu_b     = (const float*)d_in[30];
    const float* fg_w     = (const float*)d_in[31];
    const float* fg_b     = (const float*)d_in[32];
    const float* dn_w     = (const float*)d_in[33];
    const float* dn_b     = (const float*)d_in[34];
    const float* fn_w     = (const float*)d_in[35];
    const float* fn_b     = (const float*)d_in[36];
    const float* head_w   = (const float*)d_in[37];
    const float* head_b   = (const float*)d_in[38];

    float* ws = (float*)d_ws;
    float* h   = ws;                 // 100864
    float* hn  = ws + 100864;        // 100864  (also reused as attention-out buffer)
    float* Qb  = ws + 201728;        // 100864  (also reused as hn2)
    float* Kb  = ws + 302592;        // 100864  (Kb..Vb reused as `fused` [BL,256])
    float* Vb  = ws + 403456;        // 100864
    float* gb_ = ws + 504320;        // 6304
    float* out = (float*)d_out;

    k_patch_ln<<<197, 128, 0, stream>>>(x, patch_w, patch_b, cls_tok, pos_emb,
                                        bn_gamma, bn_beta, bn_rmax, bn_rrng,
                                        n1_w, n1_b, h, hn);

    for (int i = 0; i < 2; ++i) {
        k_qkvg<<<197, 128, 0, stream>>>(hn,
            wq + i * 16384, bq + i * 128, wk + i * 16384, bk + i * 128,
            wv + i * 16384, bv + i * 128, gate_w + i * 1024, gate_b + i * 8,
            Qb, Kb, Vb, gb_);

        k_attn<<<224, 256, 0, stream>>>(Qb, Kb, Vb, gb_, temp + i * 8, hn /*ao*/);

        k_proj_res_ln<128><<<197, 128, 0, stream>>>(hn /*ao*/, wo + i * 16384, bo + i * 128,
                                                    h, n2_w + i * 128, n2_b + i * 128,
                                                    Qb /*hn2*/);

        k_ffn<<<197, 256, 0, stream>>>(Qb /*hn2*/,
            tu_w + i * 32768, tu_b + i * 256,
            lf_a + i * 2048, lf_c + i * 2048, lf_gate + i * 256,
            cu_w + i * 32768, cu_b + i * 256,
            fg_w + i * 32768, fg_b + i * 256,
            Kb /*fused*/);

        const float* nlw = (i == 0) ? (n1_w + 128) : fn_w;
        const float* nlb = (i == 0) ? (n1_b + 128) : fn_b;
        k_proj_res_ln<256><<<197, 128, 0, stream>>>(Kb /*fused*/, dn_w + i * 32768, dn_b + i * 128,
                                                    h, nlw, nlb, hn);
    }

    k_head<<<16, 256, 0, stream>>>(hn, head_w, head_b, out);
}